// Round 1
// baseline (747.774 us; speedup 1.0000x reference)
//
#include <hip/hip_runtime.h>
#include <math.h>

#define B  8
#define LP1 25
#define L  24
#define T  512
#define D  1024
#define P  128
#define TOPK 3

// kernel1: t split into 4 chunks per (b,l)
#define K1_TC 4
// kernel3: t split into 32 chunks per b (16 rows each)
#define K3_TC 32

// ws float offsets
#define PSUM_OFF 0                    // B*L*K1_TC = 768 floats
#define TV_OFF   768                  // 24 floats (topk vals)
#define TI_OFF   792                  // 24 ints  (topk idx)
#define PMAX_OFF 1024                 // B*K3_TC*D = 262144 floats (16B aligned)

// d_out float offsets
#define OUT_PROJ 0                    // (8,128)   = 1024
#define OUT_SCORES 1024               // (8,24)    = 192
#define OUT_TOPK 1216                 // (8,3)     = 24 (written as float)
#define OUT_SEL 1240                  // (8,3,512,1024) ; 1240*4 % 16 == 0

__device__ __forceinline__ float blockReduceSum(float v, float* red) {
    int tid = threadIdx.x;
    #pragma unroll
    for (int o = 32; o; o >>= 1) v += __shfl_down(v, o);
    if ((tid & 63) == 0) red[tid >> 6] = v;
    __syncthreads();
    float total = red[0] + red[1] + red[2] + red[3];
    __syncthreads();
    return total;
}

// ---------------- K1: partial score sums ----------------
__global__ __launch_bounds__(256) void k1_scores(const float* __restrict__ x,
                                                 const float* __restrict__ w_score,
                                                 float* __restrict__ psum) {
    __shared__ float red[4];
    int blk = blockIdx.x;          // 0..767
    int tc  = blk & (K1_TC - 1);
    int bl  = blk >> 2;            // 0..191
    int b = bl / L, l = bl % L;
    int tid = threadIdx.x;
    const float4* xp = (const float4*)(x + ((size_t)(b * LP1 + l + 1) * T) * D);
    float4 w4 = ((const float4*)w_score)[tid];
    float acc = 0.f;
    int t0 = tc * (T / K1_TC);
    for (int t = t0; t < t0 + T / K1_TC; ++t) {
        float4 v = xp[(size_t)t * (D / 4) + tid];
        acc += v.x * w4.x + v.y * w4.y + v.z * w4.z + v.w * w4.w;
    }
    float total = blockReduceSum(acc, red);
    if (tid == 0) psum[blk] = total;
}

// ---------------- K2: scores finalize, softmax, top-3 ----------------
__global__ __launch_bounds__(256) void k2_topk(const float* __restrict__ psum,
                                               const float* __restrict__ b_score,
                                               float* __restrict__ out,
                                               float* __restrict__ tv,
                                               int* __restrict__ ti) {
    __shared__ float sc[B][L];
    int tid = threadIdx.x;
    if (tid < B * L) {
        float s = 0.f;
        #pragma unroll
        for (int c = 0; c < K1_TC; ++c) s += psum[tid * K1_TC + c];
        s = s * (1.0f / (float)T) + b_score[0];
        sc[tid / L][tid % L] = s;
        out[OUT_SCORES + tid] = s;
    }
    __syncthreads();
    if (tid < B) {
        int b = tid;
        float mx = -INFINITY;
        for (int l = 0; l < L; ++l) mx = fmaxf(mx, sc[b][l]);
        float pr[L];
        float sum = 0.f;
        for (int l = 0; l < L; ++l) { pr[l] = __expf(sc[b][l] - mx); sum += pr[l]; }
        float inv = 1.f / sum;
        for (int l = 0; l < L; ++l) pr[l] *= inv;
        for (int k = 0; k < TOPK; ++k) {
            int bi = 0; float bv = -1.f;
            for (int l = 0; l < L; ++l) {
                if (pr[l] > bv) { bv = pr[l]; bi = l; }   // strict > => first index wins (lax.top_k tie rule)
            }
            tv[b * TOPK + k] = bv;
            ti[b * TOPK + k] = bi;
            out[OUT_TOPK + b * TOPK + k] = (float)bi;
            pr[bi] = -2.f;
        }
    }
}

// ---------------- K3: gather selected layers, weighted sum, partial max over t ----------------
__global__ __launch_bounds__(256) void k3_gather(const float* __restrict__ x,
                                                 const float* __restrict__ tv,
                                                 const int* __restrict__ ti,
                                                 float* __restrict__ out_sel,
                                                 float* __restrict__ pmax) {
    int b  = blockIdx.x >> 5;       // /32
    int tc = blockIdx.x & 31;
    int tid = threadIdx.x;
    float v0 = tv[b * TOPK + 0], v1 = tv[b * TOPK + 1], v2 = tv[b * TOPK + 2];
    int i0 = ti[b * TOPK + 0], i1 = ti[b * TOPK + 1], i2 = ti[b * TOPK + 2];
    const float4* s0 = (const float4*)(x + ((size_t)(b * LP1 + i0 + 1) * T) * D);
    const float4* s1 = (const float4*)(x + ((size_t)(b * LP1 + i1 + 1) * T) * D);
    const float4* s2 = (const float4*)(x + ((size_t)(b * LP1 + i2 + 1) * T) * D);
    float4* o0 = (float4*)(out_sel + ((size_t)(b * TOPK + 0) * T) * D);
    float4* o1 = (float4*)(out_sel + ((size_t)(b * TOPK + 1) * T) * D);
    float4* o2 = (float4*)(out_sel + ((size_t)(b * TOPK + 2) * T) * D);
    float4 mx = make_float4(-INFINITY, -INFINITY, -INFINITY, -INFINITY);
    int t0 = tc * (T / K3_TC);
    for (int t = t0; t < t0 + T / K3_TC; ++t) {
        size_t off = (size_t)t * (D / 4) + tid;
        float4 a = s0[off];
        float4 c = s1[off];
        float4 e = s2[off];
        o0[off] = a; o1[off] = c; o2[off] = e;
        float4 w;
        w.x = v0 * a.x + v1 * c.x + v2 * e.x;
        w.y = v0 * a.y + v1 * c.y + v2 * e.y;
        w.z = v0 * a.z + v1 * c.z + v2 * e.z;
        w.w = v0 * a.w + v1 * c.w + v2 * e.w;
        mx.x = fmaxf(mx.x, w.x); mx.y = fmaxf(mx.y, w.y);
        mx.z = fmaxf(mx.z, w.z); mx.w = fmaxf(mx.w, w.w);
    }
    ((float4*)pmax)[(size_t)(b * K3_TC + tc) * (D / 4) + tid] = mx;
}

// ---------------- K4: max-combine, layernorm, projection ----------------
__global__ __launch_bounds__(256) void k4_ln_proj(const float* __restrict__ pmax,
                                                  const float* __restrict__ gamma,
                                                  const float* __restrict__ beta,
                                                  const float* __restrict__ wproj,
                                                  const float* __restrict__ bproj,
                                                  float* __restrict__ out) {
    __shared__ float red[4];
    __shared__ float nrm[D];
    __shared__ float part[256];
    int b = blockIdx.x, tid = threadIdx.x;
    const float4* pm = (const float4*)(pmax + (size_t)b * K3_TC * D);
    float4 m = make_float4(-INFINITY, -INFINITY, -INFINITY, -INFINITY);
    #pragma unroll
    for (int c = 0; c < K3_TC; ++c) {
        float4 v = pm[(size_t)c * (D / 4) + tid];
        m.x = fmaxf(m.x, v.x); m.y = fmaxf(m.y, v.y);
        m.z = fmaxf(m.z, v.z); m.w = fmaxf(m.w, v.w);
    }
    float s = m.x + m.y + m.z + m.w;
    float S = blockReduceSum(s, red);
    float mean = S * (1.0f / (float)D);
    float dx0 = m.x - mean, dx1 = m.y - mean, dx2 = m.z - mean, dx3 = m.w - mean;
    float q = dx0 * dx0 + dx1 * dx1 + dx2 * dx2 + dx3 * dx3;
    float Q = blockReduceSum(q, red);
    float var = Q * (1.0f / (float)D);
    float r = rsqrtf(var + 1e-5f);
    float4 g = ((const float4*)gamma)[tid];
    float4 bt = ((const float4*)beta)[tid];
    nrm[tid * 4 + 0] = dx0 * r * g.x + bt.x;
    nrm[tid * 4 + 1] = dx1 * r * g.y + bt.y;
    nrm[tid * 4 + 2] = dx2 * r * g.z + bt.z;
    nrm[tid * 4 + 3] = dx3 * r * g.w + bt.w;
    __syncthreads();
    int p = tid & (P - 1);
    int h = tid >> 7;           // 0 or 1: which half of D
    float acc = 0.f;
    for (int d = h * (D / 2); d < (h + 1) * (D / 2); ++d)
        acc += nrm[d] * wproj[(size_t)d * P + p];
    part[tid] = acc;
    __syncthreads();
    if (tid < P) out[(size_t)b * P + tid] = part[tid] + part[tid + P] + bproj[tid];
}

extern "C" void kernel_launch(void* const* d_in, const int* in_sizes, int n_in,
                              void* d_out, int out_size, void* d_ws, size_t ws_size,
                              hipStream_t stream) {
    const float* x       = (const float*)d_in[0];  // (8,25,512,1024)
    const float* w_score = (const float*)d_in[1];  // (1024,1)
    const float* b_score = (const float*)d_in[2];  // (1,)
    const float* gamma   = (const float*)d_in[3];  // (1024,)
    const float* beta    = (const float*)d_in[4];  // (1024,)
    const float* wproj   = (const float*)d_in[5];  // (1024,128)
    const float* bproj   = (const float*)d_in[6];  // (128,)
    float* out = (float*)d_out;
    float* ws  = (float*)d_ws;

    float* psum = ws + PSUM_OFF;
    float* tv   = ws + TV_OFF;
    int*   ti   = (int*)(ws + TI_OFF);
    float* pmax = ws + PMAX_OFF;

    k1_scores<<<B * L * K1_TC, 256, 0, stream>>>(x, w_score, psum);
    k2_topk<<<1, 256, 0, stream>>>(psum, b_score, out, tv, ti);
    k3_gather<<<B * K3_TC, 256, 0, stream>>>(x, tv, ti, out + OUT_SEL, pmax);
    k4_ln_proj<<<B, 256, 0, stream>>>(pmax, gamma, beta, wproj, bproj, out + OUT_PROJ);
}

// Round 3
// 601.966 us; speedup vs baseline: 1.2422x; 1.2422x over previous
//
#include <hip/hip_runtime.h>
#include <math.h>

#define B  8
#define LP1 25
#define L  24
#define T  512
#define D  1024
#define P  128
#define TOPK 3

typedef float v4f __attribute__((ext_vector_type(4)));

// kernel1: t split into 8 chunks per (b,l) -> 1536 blocks (6/CU)
#define K1_TC 8
// kernel3: t split into 64 chunks per b (8 rows each) -> 512 blocks (2/CU)
#define K3_TC 64

// ws float offsets
#define PSUM_OFF 0                    // B*L*K1_TC = 1536 floats
#define TV_OFF   1536                 // 24 floats (topk vals)
#define TI_OFF   1560                 // 24 ints  (topk idx)
#define PMAX_OFF 1600                 // B*K3_TC*D = 524288 floats; 1600*4%16==0
// d_out float offsets
#define OUT_PROJ 0                    // (8,128)   = 1024
#define OUT_SCORES 1024               // (8,24)    = 192
#define OUT_TOPK 1216                 // (8,3)     = 24 (written as float)
#define OUT_SEL 1240                  // (8,3,512,1024) ; 1240*4 % 16 == 0

__device__ __forceinline__ float blockReduceSum(float v, float* red) {
    int tid = threadIdx.x;
    #pragma unroll
    for (int o = 32; o; o >>= 1) v += __shfl_down(v, o);
    if ((tid & 63) == 0) red[tid >> 6] = v;
    __syncthreads();
    float total = red[0] + red[1] + red[2] + red[3];
    __syncthreads();
    return total;
}

// ---------------- K1: partial score sums ----------------
__global__ __launch_bounds__(256) void k1_scores(const float* __restrict__ x,
                                                 const float* __restrict__ w_score,
                                                 float* __restrict__ psum) {
    __shared__ float red[4];
    int blk = blockIdx.x;          // 0..1535
    int tc  = blk & (K1_TC - 1);
    int bl  = blk >> 3;            // 0..191
    int b = bl / L, l = bl % L;
    int tid = threadIdx.x;
    const v4f* xp = (const v4f*)(x + ((size_t)(b * LP1 + l + 1) * T) * D);
    v4f w4 = ((const v4f*)w_score)[tid];
    float acc0 = 0.f, acc1 = 0.f;
    int t0 = tc * (T / K1_TC);
    #pragma unroll 4
    for (int t = t0; t < t0 + T / K1_TC; t += 2) {
        v4f v0 = xp[(size_t)t * (D / 4) + tid];
        v4f v1 = xp[(size_t)(t + 1) * (D / 4) + tid];
        acc0 += v0.x * w4.x + v0.y * w4.y + v0.z * w4.z + v0.w * w4.w;
        acc1 += v1.x * w4.x + v1.y * w4.y + v1.z * w4.z + v1.w * w4.w;
    }
    float total = blockReduceSum(acc0 + acc1, red);
    if (tid == 0) psum[blk] = total;
}

// ---------------- K2: scores finalize, softmax, top-3 ----------------
__global__ __launch_bounds__(256) void k2_topk(const float* __restrict__ psum,
                                               const float* __restrict__ b_score,
                                               float* __restrict__ out,
                                               float* __restrict__ tv,
                                               int* __restrict__ ti) {
    __shared__ float sc[B][L];
    int tid = threadIdx.x;
    if (tid < B * L) {
        float s = 0.f;
        #pragma unroll
        for (int c = 0; c < K1_TC; ++c) s += psum[tid * K1_TC + c];
        s = s * (1.0f / (float)T) + b_score[0];
        sc[tid / L][tid % L] = s;
        out[OUT_SCORES + tid] = s;
    }
    __syncthreads();
    if (tid < B) {
        int b = tid;
        float mx = -INFINITY;
        for (int l = 0; l < L; ++l) mx = fmaxf(mx, sc[b][l]);
        float pr[L];
        float sum = 0.f;
        for (int l = 0; l < L; ++l) { pr[l] = __expf(sc[b][l] - mx); sum += pr[l]; }
        float inv = 1.f / sum;
        for (int l = 0; l < L; ++l) pr[l] *= inv;
        for (int k = 0; k < TOPK; ++k) {
            int bi = 0; float bv = -1.f;
            for (int l = 0; l < L; ++l) {
                if (pr[l] > bv) { bv = pr[l]; bi = l; }   // strict > => first index wins (lax.top_k tie rule)
            }
            tv[b * TOPK + k] = bv;
            ti[b * TOPK + k] = bi;
            out[OUT_TOPK + b * TOPK + k] = (float)bi;
            pr[bi] = -2.f;
        }
    }
}

// ---------------- K3: gather selected layers, weighted sum, partial max over t ----------------
__global__ __launch_bounds__(256) void k3_gather(const float* __restrict__ x,
                                                 const float* __restrict__ tv,
                                                 const int* __restrict__ ti,
                                                 float* __restrict__ out_sel,
                                                 float* __restrict__ pmax) {
    int b  = blockIdx.x >> 6;       // /64
    int tc = blockIdx.x & 63;
    int tid = threadIdx.x;
    float v0 = tv[b * TOPK + 0], v1 = tv[b * TOPK + 1], v2 = tv[b * TOPK + 2];
    int i0 = ti[b * TOPK + 0], i1 = ti[b * TOPK + 1], i2 = ti[b * TOPK + 2];
    const v4f* s0 = (const v4f*)(x + ((size_t)(b * LP1 + i0 + 1) * T) * D);
    const v4f* s1 = (const v4f*)(x + ((size_t)(b * LP1 + i1 + 1) * T) * D);
    const v4f* s2 = (const v4f*)(x + ((size_t)(b * LP1 + i2 + 1) * T) * D);
    v4f* o0 = (v4f*)(out_sel + ((size_t)(b * TOPK + 0) * T) * D);
    v4f* o1 = (v4f*)(out_sel + ((size_t)(b * TOPK + 1) * T) * D);
    v4f* o2 = (v4f*)(out_sel + ((size_t)(b * TOPK + 2) * T) * D);
    v4f mx = (v4f){-INFINITY, -INFINITY, -INFINITY, -INFINITY};
    int t0 = tc * (T / K3_TC);
    #pragma unroll
    for (int t = t0; t < t0 + T / K3_TC; ++t) {
        size_t off = (size_t)t * (D / 4) + tid;
        v4f a = s0[off];
        v4f c = s1[off];
        v4f e = s2[off];
        __builtin_nontemporal_store(a, &o0[off]);
        __builtin_nontemporal_store(c, &o1[off]);
        __builtin_nontemporal_store(e, &o2[off]);
        v4f w = v0 * a + v1 * c + v2 * e;
        mx.x = fmaxf(mx.x, w.x); mx.y = fmaxf(mx.y, w.y);
        mx.z = fmaxf(mx.z, w.z); mx.w = fmaxf(mx.w, w.w);
    }
    ((v4f*)pmax)[(size_t)(b * K3_TC + tc) * (D / 4) + tid] = mx;
}

// ---------------- K4: max-combine, layernorm, projection ----------------
__global__ __launch_bounds__(256) void k4_ln_proj(const float* __restrict__ pmax,
                                                  const float* __restrict__ gamma,
                                                  const float* __restrict__ beta,
                                                  const float* __restrict__ wproj,
                                                  const float* __restrict__ bproj,
                                                  float* __restrict__ out) {
    __shared__ float red[4];
    __shared__ float nrm[D];
    __shared__ float part[256];
    int b = blockIdx.x, tid = threadIdx.x;
    const v4f* pm = (const v4f*)(pmax + (size_t)b * K3_TC * D);
    v4f m = (v4f){-INFINITY, -INFINITY, -INFINITY, -INFINITY};
    #pragma unroll
    for (int c = 0; c < K3_TC; ++c) {
        v4f v = pm[(size_t)c * (D / 4) + tid];
        m.x = fmaxf(m.x, v.x); m.y = fmaxf(m.y, v.y);
        m.z = fmaxf(m.z, v.z); m.w = fmaxf(m.w, v.w);
    }
    float s = m.x + m.y + m.z + m.w;
    float S = blockReduceSum(s, red);
    float mean = S * (1.0f / (float)D);
    float dx0 = m.x - mean, dx1 = m.y - mean, dx2 = m.z - mean, dx3 = m.w - mean;
    float q = dx0 * dx0 + dx1 * dx1 + dx2 * dx2 + dx3 * dx3;
    float Q = blockReduceSum(q, red);
    float var = Q * (1.0f / (float)D);
    float r = rsqrtf(var + 1e-5f);
    v4f g = ((const v4f*)gamma)[tid];
    v4f bt = ((const v4f*)beta)[tid];
    nrm[tid * 4 + 0] = dx0 * r * g.x + bt.x;
    nrm[tid * 4 + 1] = dx1 * r * g.y + bt.y;
    nrm[tid * 4 + 2] = dx2 * r * g.z + bt.z;
    nrm[tid * 4 + 3] = dx3 * r * g.w + bt.w;
    __syncthreads();
    int p = tid & (P - 1);
    int h = tid >> 7;           // 0 or 1: which half of D
    float acc = 0.f;
    #pragma unroll 8
    for (int d = h * (D / 2); d < (h + 1) * (D / 2); ++d)
        acc += nrm[d] * wproj[(size_t)d * P + p];
    part[tid] = acc;
    __syncthreads();
    if (tid < P) out[(size_t)b * P + tid] = part[tid] + part[tid + P] + bproj[tid];
}

extern "C" void kernel_launch(void* const* d_in, const int* in_sizes, int n_in,
                              void* d_out, int out_size, void* d_ws, size_t ws_size,
                              hipStream_t stream) {
    const float* x       = (const float*)d_in[0];  // (8,25,512,1024)
    const float* w_score = (const float*)d_in[1];  // (1024,1)
    const float* b_score = (const float*)d_in[2];  // (1,)
    const float* gamma   = (const float*)d_in[3];  // (1024,)
    const float* beta    = (const float*)d_in[4];  // (1024,)
    const float* wproj   = (const float*)d_in[5];  // (1024,128)
    const float* bproj   = (const float*)d_in[6];  // (128,)
    float* out = (float*)d_out;
    float* ws  = (float*)d_ws;

    float* psum = ws + PSUM_OFF;
    float* tv   = ws + TV_OFF;
    int*   ti   = (int*)(ws + TI_OFF);
    float* pmax = ws + PMAX_OFF;

    k1_scores<<<B * L * K1_TC, 256, 0, stream>>>(x, w_score, psum);
    k2_topk<<<1, 256, 0, stream>>>(psum, b_score, out, tv, ti);
    k3_gather<<<B * K3_TC, 256, 0, stream>>>(x, tv, ti, out + OUT_SEL, pmax);
    k4_ln_proj<<<B, 256, 0, stream>>>(pmax, gamma, beta, wproj, bproj, out + OUT_PROJ);
}